// Round 1
// baseline (214.253 us; speedup 1.0000x reference)
//
#include <hip/hip_runtime.h>

#define T_TOK 1024
#define NEXP 8
#define HID 1024
#define INTER 2048
#define SLOT_CAP (T_TOK * 2 + 128)

#define BM 128
#define BN 128
#define BK 32
#define LDK 40  // padded K stride in LDS (bf16 elems): 80B rows, 16B-aligned

typedef __bf16 bf16x8 __attribute__((ext_vector_type(8)));
typedef __bf16 bf16x4 __attribute__((ext_vector_type(4)));
typedef float f32x4 __attribute__((ext_vector_type(4)));

// ---- workspace layout (bytes) ----
#define WS_COUNTS 0
#define WS_OFFSETS 64
#define WS_TEXPERT 128
#define WS_TGATE (WS_TEXPERT + T_TOK * 2 * 4)
#define WS_TRANK (WS_TGATE + T_TOK * 2 * 4)
#define WS_TOKEN_OF (WS_TRANK + T_TOK * 2 * 4)
#define WS_GATE_OF (WS_TOKEN_OF + SLOT_CAP * 4)
#define WS_ABUF 65536  // bf16 a[SLOT_CAP][INTER] ~ 8.9 MB

// ---------------- router: softmax + top-2 ----------------
__global__ void moe_router(const float* __restrict__ logits, int* __restrict__ counts,
                           int* __restrict__ t_expert, float* __restrict__ t_gate,
                           int* __restrict__ t_rank) {
  int t = blockIdx.x * blockDim.x + threadIdx.x;
  if (t >= T_TOK) return;
  float l[NEXP];
  float mx = -1e30f;
#pragma unroll
  for (int e = 0; e < NEXP; ++e) {
    l[e] = logits[t * NEXP + e];
    mx = fmaxf(mx, l[e]);
  }
  float s = 0.f;
#pragma unroll
  for (int e = 0; e < NEXP; ++e) {
    l[e] = __expf(l[e] - mx);
    s += l[e];
  }
  float inv = 1.f / s;
  int i0 = 0;
#pragma unroll
  for (int e = 1; e < NEXP; ++e)
    if (l[e] > l[i0]) i0 = e;
  int i1 = (i0 == 0) ? 1 : 0;
#pragma unroll
  for (int e = 0; e < NEXP; ++e)
    if (e != i0 && e != i1 && l[e] > l[i1]) i1 = e;
  int es[2] = {i0, i1};
#pragma unroll
  for (int k = 0; k < 2; ++k) {
    int e = es[k];
    int r = atomicAdd(&counts[e], 1);
    int p = t * 2 + k;
    t_expert[p] = e;
    t_gate[p] = l[e] * inv;
    t_rank[p] = r;
  }
}

// ---------------- assign: prefix + slot maps ----------------
__global__ void moe_assign(const int* __restrict__ counts, int* __restrict__ offsets,
                           const int* __restrict__ t_expert, const float* __restrict__ t_gate,
                           const int* __restrict__ t_rank, int* __restrict__ token_of,
                           float* __restrict__ gate_of) {
  __shared__ int off_s[NEXP];
  if (threadIdx.x == 0) {
    int s = 0;
    for (int e = 0; e < NEXP; ++e) {
      off_s[e] = s;
      offsets[e] = s;
      s += counts[e];
    }
  }
  __syncthreads();
  for (int p = threadIdx.x; p < T_TOK * 2; p += blockDim.x) {
    int e = t_expert[p];
    int slot = off_s[e] + t_rank[p];
    token_of[slot] = p >> 1;
    gate_of[slot] = t_gate[p];
  }
}

// ---------------- GEMM1: h,u = Xg @ {w1,w3}; a = silu(h)*u ----------------
__global__ __launch_bounds__(256, 2) void moe_gemm1(
    const float* __restrict__ x, const float* __restrict__ w1, const float* __restrict__ w3,
    const int* __restrict__ offsets, const int* __restrict__ counts,
    const int* __restrict__ token_of, __bf16* __restrict__ abuf) {
  const int e = blockIdx.z;
  const int n_e = counts[e];
  const int rt = blockIdx.y;
  if (rt * BM >= n_e) return;
  const int off_e = offsets[e];
  const int col0 = blockIdx.x * BN;
  const int tid = threadIdx.x;
  const int lane = tid & 63;
  const int wid = tid >> 6;
  const int wr = (wid >> 1) * 64;  // wave row origin in tile
  const int wc = (wid & 1) * 64;   // wave col origin in tile

  __shared__ __bf16 aL[BM][LDK];   // [row][k]
  __shared__ __bf16 b1L[BN][LDK];  // [col][k]
  __shared__ __bf16 b3L[BN][LDK];

  f32x4 acc_h[4][4], acc_u[4][4];
#pragma unroll
  for (int m = 0; m < 4; ++m)
#pragma unroll
    for (int n = 0; n < 4; ++n) {
      acc_h[m][n] = (f32x4){0.f, 0.f, 0.f, 0.f};
      acc_u[m][n] = (f32x4){0.f, 0.f, 0.f, 0.f};
    }

  // A staging assignment: 1024 float4 chunks; q = tid + 256*i → row=q>>3, kq=q&7
  const float* aptr[4];
#pragma unroll
  for (int i = 0; i < 4; ++i) {
    int q = tid + 256 * i;
    int row = q >> 3;
    int r_loc = rt * BM + row;
    int tok = (r_loc < n_e) ? token_of[off_e + r_loc] : -1;
    aptr[i] = (tok >= 0) ? (x + (size_t)tok * HID + (q & 7) * 4) : nullptr;
  }
  // B staging assignment: cq = tid&31 (4 cols), kq = tid>>5 (4 k-rows)
  const int cq = tid & 31, kq = tid >> 5;
  const float* w1p = w1 + (size_t)e * HID * INTER + (size_t)(kq * 4) * INTER + col0 + cq * 4;
  const float* w3p = w3 + (size_t)e * HID * INTER + (size_t)(kq * 4) * INTER + col0 + cq * 4;

  const int lr = lane & 15, lg = lane >> 4;

  for (int k0 = 0; k0 < HID; k0 += BK) {
    __syncthreads();
    // ---- stage A (gathered token rows, fp32 -> bf16) ----
#pragma unroll
    for (int i = 0; i < 4; ++i) {
      int q = tid + 256 * i;
      int row = q >> 3, kqa = q & 7;
      float4 v = make_float4(0.f, 0.f, 0.f, 0.f);
      if (aptr[i]) v = *(const float4*)(aptr[i] + k0);
      bf16x4 pv = {(__bf16)v.x, (__bf16)v.y, (__bf16)v.z, (__bf16)v.w};
      *(bf16x4*)&aL[row][kqa * 4] = pv;
    }
    // ---- stage B1/B3 (fp32 -> bf16, transpose to [col][k]) ----
    {
      const float* p = w1p + (size_t)k0 * INTER;
      float4 r0 = *(const float4*)p;
      float4 r1 = *(const float4*)(p + INTER);
      float4 r2 = *(const float4*)(p + 2 * INTER);
      float4 r3 = *(const float4*)(p + 3 * INTER);
      bf16x4 c0 = {(__bf16)r0.x, (__bf16)r1.x, (__bf16)r2.x, (__bf16)r3.x};
      bf16x4 c1 = {(__bf16)r0.y, (__bf16)r1.y, (__bf16)r2.y, (__bf16)r3.y};
      bf16x4 c2 = {(__bf16)r0.z, (__bf16)r1.z, (__bf16)r2.z, (__bf16)r3.z};
      bf16x4 c3 = {(__bf16)r0.w, (__bf16)r1.w, (__bf16)r2.w, (__bf16)r3.w};
      *(bf16x4*)&b1L[cq * 4 + 0][kq * 4] = c0;
      *(bf16x4*)&b1L[cq * 4 + 1][kq * 4] = c1;
      *(bf16x4*)&b1L[cq * 4 + 2][kq * 4] = c2;
      *(bf16x4*)&b1L[cq * 4 + 3][kq * 4] = c3;
    }
    {
      const float* p = w3p + (size_t)k0 * INTER;
      float4 r0 = *(const float4*)p;
      float4 r1 = *(const float4*)(p + INTER);
      float4 r2 = *(const float4*)(p + 2 * INTER);
      float4 r3 = *(const float4*)(p + 3 * INTER);
      bf16x4 c0 = {(__bf16)r0.x, (__bf16)r1.x, (__bf16)r2.x, (__bf16)r3.x};
      bf16x4 c1 = {(__bf16)r0.y, (__bf16)r1.y, (__bf16)r2.y, (__bf16)r3.y};
      bf16x4 c2 = {(__bf16)r0.z, (__bf16)r1.z, (__bf16)r2.z, (__bf16)r3.z};
      bf16x4 c3 = {(__bf16)r0.w, (__bf16)r1.w, (__bf16)r2.w, (__bf16)r3.w};
      *(bf16x4*)&b3L[cq * 4 + 0][kq * 4] = c0;
      *(bf16x4*)&b3L[cq * 4 + 1][kq * 4] = c1;
      *(bf16x4*)&b3L[cq * 4 + 2][kq * 4] = c2;
      *(bf16x4*)&b3L[cq * 4 + 3][kq * 4] = c3;
    }
    __syncthreads();
    // ---- fragments + MFMA ----
    bf16x8 af[4], bf1[4], bf3[4];
#pragma unroll
    for (int m = 0; m < 4; ++m) af[m] = *(const bf16x8*)&aL[wr + m * 16 + lr][lg * 8];
#pragma unroll
    for (int n = 0; n < 4; ++n) {
      bf1[n] = *(const bf16x8*)&b1L[wc + n * 16 + lr][lg * 8];
      bf3[n] = *(const bf16x8*)&b3L[wc + n * 16 + lr][lg * 8];
    }
#pragma unroll
    for (int m = 0; m < 4; ++m)
#pragma unroll
      for (int n = 0; n < 4; ++n) {
        acc_h[m][n] = __builtin_amdgcn_mfma_f32_16x16x32_bf16(af[m], bf1[n], acc_h[m][n], 0, 0, 0);
        acc_u[m][n] = __builtin_amdgcn_mfma_f32_16x16x32_bf16(af[m], bf3[n], acc_u[m][n], 0, 0, 0);
      }
  }

  // ---- epilogue: a = silu(h) * u, store bf16 ----
#pragma unroll
  for (int m = 0; m < 4; ++m)
#pragma unroll
    for (int n = 0; n < 4; ++n) {
      int col = col0 + wc + n * 16 + lr;
#pragma unroll
      for (int r = 0; r < 4; ++r) {
        int row_loc = rt * BM + wr + m * 16 + lg * 4 + r;
        if (row_loc < n_e) {
          float h = acc_h[m][n][r];
          float u = acc_u[m][n][r];
          float a = h / (1.f + __expf(-h)) * u;
          abuf[(size_t)(off_e + row_loc) * INTER + col] = (__bf16)a;
        }
      }
    }
}

// ---------------- GEMM2: y = a @ w2; out += gate*y ----------------
__global__ __launch_bounds__(256, 2) void moe_gemm2(
    const __bf16* __restrict__ abuf, const float* __restrict__ w2,
    const int* __restrict__ offsets, const int* __restrict__ counts,
    const int* __restrict__ token_of, const float* __restrict__ gate_of,
    float* __restrict__ out) {
  const int e = blockIdx.z;
  const int n_e = counts[e];
  const int rt = blockIdx.y;
  if (rt * BM >= n_e) return;
  const int off_e = offsets[e];
  const int col0 = blockIdx.x * BN;
  const int tid = threadIdx.x;
  const int lane = tid & 63;
  const int wid = tid >> 6;
  const int wr = (wid >> 1) * 64;
  const int wc = (wid & 1) * 64;

  __shared__ __bf16 aL[BM][LDK];
  __shared__ __bf16 bL[BN][LDK];

  f32x4 acc[4][4];
#pragma unroll
  for (int m = 0; m < 4; ++m)
#pragma unroll
    for (int n = 0; n < 4; ++n) acc[m][n] = (f32x4){0.f, 0.f, 0.f, 0.f};

  const __bf16* ap = abuf + (size_t)(off_e + rt * BM) * INTER;
  const int cq = tid & 31, kq = tid >> 5;
  const float* w2p = w2 + (size_t)e * INTER * HID + (size_t)(kq * 4) * HID + col0 + cq * 4;

  const int lr = lane & 15, lg = lane >> 4;

  for (int k0 = 0; k0 < INTER; k0 += BK) {
    __syncthreads();
    // ---- stage A (already bf16, contiguous slots) ----
#pragma unroll
    for (int i = 0; i < 2; ++i) {
      int q = tid + 256 * i;
      int row = q >> 2, kc = q & 3;
      bf16x8 v = *(const bf16x8*)(ap + (size_t)row * INTER + k0 + kc * 8);
      *(bf16x8*)&aL[row][kc * 8] = v;
    }
    // ---- stage B (w2 fp32 -> bf16, transpose to [col][k]) ----
    {
      const float* p = w2p + (size_t)k0 * HID;
      float4 r0 = *(const float4*)p;
      float4 r1 = *(const float4*)(p + HID);
      float4 r2 = *(const float4*)(p + 2 * HID);
      float4 r3 = *(const float4*)(p + 3 * HID);
      bf16x4 c0 = {(__bf16)r0.x, (__bf16)r1.x, (__bf16)r2.x, (__bf16)r3.x};
      bf16x4 c1 = {(__bf16)r0.y, (__bf16)r1.y, (__bf16)r2.y, (__bf16)r3.y};
      bf16x4 c2 = {(__bf16)r0.z, (__bf16)r1.z, (__bf16)r2.z, (__bf16)r3.z};
      bf16x4 c3 = {(__bf16)r0.w, (__bf16)r1.w, (__bf16)r2.w, (__bf16)r3.w};
      *(bf16x4*)&bL[cq * 4 + 0][kq * 4] = c0;
      *(bf16x4*)&bL[cq * 4 + 1][kq * 4] = c1;
      *(bf16x4*)&bL[cq * 4 + 2][kq * 4] = c2;
      *(bf16x4*)&bL[cq * 4 + 3][kq * 4] = c3;
    }
    __syncthreads();
    bf16x8 af[4], bf[4];
#pragma unroll
    for (int m = 0; m < 4; ++m) af[m] = *(const bf16x8*)&aL[wr + m * 16 + lr][lg * 8];
#pragma unroll
    for (int n = 0; n < 4; ++n) bf[n] = *(const bf16x8*)&bL[wc + n * 16 + lr][lg * 8];
#pragma unroll
    for (int m = 0; m < 4; ++m)
#pragma unroll
      for (int n = 0; n < 4; ++n)
        acc[m][n] = __builtin_amdgcn_mfma_f32_16x16x32_bf16(af[m], bf[n], acc[m][n], 0, 0, 0);
  }

  // ---- epilogue: out[token] += gate * y (exactly 2 adds per element) ----
#pragma unroll
  for (int m = 0; m < 4; ++m)
#pragma unroll
    for (int n = 0; n < 4; ++n) {
      int col = col0 + wc + n * 16 + lr;
#pragma unroll
      for (int r = 0; r < 4; ++r) {
        int row_loc = rt * BM + wr + m * 16 + lg * 4 + r;
        if (row_loc < n_e) {
          int slot = off_e + row_loc;
          atomicAdd(&out[(size_t)token_of[slot] * HID + col], gate_of[slot] * acc[m][n][r]);
        }
      }
    }
}

// ---------------- launch ----------------
extern "C" void kernel_launch(void* const* d_in, const int* in_sizes, int n_in,
                              void* d_out, int out_size, void* d_ws, size_t ws_size,
                              hipStream_t stream) {
  const float* x = (const float*)d_in[0];
  const float* logits = (const float*)d_in[1];
  const float* w1 = (const float*)d_in[2];
  const float* w3 = (const float*)d_in[3];
  const float* w2 = (const float*)d_in[4];
  float* out = (float*)d_out;
  char* ws = (char*)d_ws;

  int* counts = (int*)(ws + WS_COUNTS);
  int* offsets = (int*)(ws + WS_OFFSETS);
  int* t_expert = (int*)(ws + WS_TEXPERT);
  float* t_gate = (float*)(ws + WS_TGATE);
  int* t_rank = (int*)(ws + WS_TRANK);
  int* token_of = (int*)(ws + WS_TOKEN_OF);
  float* gate_of = (float*)(ws + WS_GATE_OF);
  __bf16* abuf = (__bf16*)(ws + WS_ABUF);

  hipMemsetAsync(counts, 0, 64, stream);
  hipMemsetAsync(out, 0, (size_t)out_size * sizeof(float), stream);
  moe_router<<<dim3(4), dim3(256), 0, stream>>>(logits, counts, t_expert, t_gate, t_rank);
  moe_assign<<<dim3(1), dim3(256), 0, stream>>>(counts, offsets, t_expert, t_gate, t_rank,
                                                token_of, gate_of);
  moe_gemm1<<<dim3(INTER / BN, 8, NEXP), dim3(256), 0, stream>>>(x, w1, w3, offsets, counts,
                                                                 token_of, abuf);
  moe_gemm2<<<dim3(HID / BN, 8, NEXP), dim3(256), 0, stream>>>(abuf, w2, offsets, counts,
                                                               token_of, gate_of, out);
}

// Round 3
// 202.936 us; speedup vs baseline: 1.0558x; 1.0558x over previous
//
#include <hip/hip_runtime.h>

#define T_TOK 1024
#define NEXP 8
#define HID 1024
#define INTER 2048
#define SLOT_CAP (T_TOK * 2 + 128)

#define BK 32
#define LDK 40  // padded K stride in LDS (bf16 elems): 80B rows, 16B-aligned
#define SPLITK 4
#define KCHUNK (INTER / SPLITK)  // 512

typedef __bf16 bf16x8 __attribute__((ext_vector_type(8)));
typedef __bf16 bf16x4 __attribute__((ext_vector_type(4)));
typedef float f32x4 __attribute__((ext_vector_type(4)));

// ---- workspace layout (bytes) ----
#define WS_COUNTS 0
#define WS_OFFSETS 64
#define WS_TEXPERT 128
#define WS_TGATE (WS_TEXPERT + T_TOK * 2 * 4)
#define WS_TRANK (WS_TGATE + T_TOK * 2 * 4)
#define WS_TOKEN_OF (WS_TRANK + T_TOK * 2 * 4)
#define WS_GATE_OF (WS_TOKEN_OF + SLOT_CAP * 4)
#define WS_ABUF 65536                                   // bf16 a[SLOT_CAP][INTER] = 8,912,896 B
#define WS_YP (WS_ABUF + SLOT_CAP * INTER * 2)          // fp32 yp[SPLITK][T][H] = 16,777,216 B

// ---------------- router: softmax + top-2 ----------------
__global__ void moe_router(const float* __restrict__ logits, int* __restrict__ counts,
                           int* __restrict__ t_expert, float* __restrict__ t_gate,
                           int* __restrict__ t_rank) {
  int t = blockIdx.x * blockDim.x + threadIdx.x;
  if (t >= T_TOK) return;
  float l[NEXP];
  float mx = -1e30f;
#pragma unroll
  for (int e = 0; e < NEXP; ++e) {
    l[e] = logits[t * NEXP + e];
    mx = fmaxf(mx, l[e]);
  }
  float s = 0.f;
#pragma unroll
  for (int e = 0; e < NEXP; ++e) {
    l[e] = __expf(l[e] - mx);
    s += l[e];
  }
  float inv = 1.f / s;
  int i0 = 0;
#pragma unroll
  for (int e = 1; e < NEXP; ++e)
    if (l[e] > l[i0]) i0 = e;
  int i1 = (i0 == 0) ? 1 : 0;
#pragma unroll
  for (int e = 0; e < NEXP; ++e)
    if (e != i0 && e != i1 && l[e] > l[i1]) i1 = e;
  int es[2] = {i0, i1};
#pragma unroll
  for (int k = 0; k < 2; ++k) {
    int e = es[k];
    int r = atomicAdd(&counts[e], 1);
    int p = t * 2 + k;
    t_expert[p] = e;
    t_gate[p] = l[e] * inv;
    t_rank[p] = r;
  }
}

// ---------------- assign: prefix + slot maps ----------------
__global__ void moe_assign(const int* __restrict__ counts, int* __restrict__ offsets,
                           const int* __restrict__ t_expert, const float* __restrict__ t_gate,
                           const int* __restrict__ t_rank, int* __restrict__ token_of,
                           float* __restrict__ gate_of) {
  __shared__ int off_s[NEXP];
  if (threadIdx.x == 0) {
    int s = 0;
    for (int e = 0; e < NEXP; ++e) {
      off_s[e] = s;
      offsets[e] = s;
      s += counts[e];
    }
  }
  __syncthreads();
  for (int p = threadIdx.x; p < T_TOK * 2; p += blockDim.x) {
    int e = t_expert[p];
    int slot = off_s[e] + t_rank[p];
    token_of[slot] = p >> 1;
    gate_of[slot] = t_gate[p];
  }
}

// transpose-convert a float4 row quad into 4 bf16 column chunks
#define TRANSPOSE_STORE(dst, r0, r1, r2, r3, cbase, kbase4)                    \
  {                                                                            \
    bf16x4 c0 = {(__bf16)r0.x, (__bf16)r1.x, (__bf16)r2.x, (__bf16)r3.x};      \
    bf16x4 c1 = {(__bf16)r0.y, (__bf16)r1.y, (__bf16)r2.y, (__bf16)r3.y};      \
    bf16x4 c2 = {(__bf16)r0.z, (__bf16)r1.z, (__bf16)r2.z, (__bf16)r3.z};      \
    bf16x4 c3 = {(__bf16)r0.w, (__bf16)r1.w, (__bf16)r2.w, (__bf16)r3.w};      \
    *(bf16x4*)&dst[(cbase) + 0][kbase4] = c0;                                  \
    *(bf16x4*)&dst[(cbase) + 1][kbase4] = c1;                                  \
    *(bf16x4*)&dst[(cbase) + 2][kbase4] = c2;                                  \
    *(bf16x4*)&dst[(cbase) + 3][kbase4] = c3;                                  \
  }

// ---------------- GEMM1: h,u = Xg @ {w1,w3}; a = silu(h)*u ----------------
// BM=64, BN=128, 4 waves (2 row x 2 col), wave tile 32x64
__global__ __launch_bounds__(256, 2) void moe_gemm1(
    const float* __restrict__ x, const float* __restrict__ w1, const float* __restrict__ w3,
    const int* __restrict__ offsets, const int* __restrict__ counts,
    const int* __restrict__ token_of, __bf16* __restrict__ abuf) {
  const int e = blockIdx.z;
  const int n_e = counts[e];
  const int rt = blockIdx.y;
  if (rt * 64 >= n_e) return;
  const int off_e = offsets[e];
  const int col0 = blockIdx.x * 128;
  const int tid = threadIdx.x;
  const int lane = tid & 63;
  const int wid = tid >> 6;
  const int wr = (wid >> 1) * 32;
  const int wc = (wid & 1) * 64;

  __shared__ __bf16 aL[64][LDK];
  __shared__ __bf16 b1L[128][LDK];
  __shared__ __bf16 b3L[128][LDK];

  f32x4 acc_h[2][4], acc_u[2][4];
#pragma unroll
  for (int m = 0; m < 2; ++m)
#pragma unroll
    for (int n = 0; n < 4; ++n) {
      acc_h[m][n] = (f32x4){0.f, 0.f, 0.f, 0.f};
      acc_u[m][n] = (f32x4){0.f, 0.f, 0.f, 0.f};
    }

  // A staging: 64 rows x 8 float4-chunks = 512; thread does 2
  const float* aptr[2];
  int arow[2], akq[2];
#pragma unroll
  for (int i = 0; i < 2; ++i) {
    int q = tid + 256 * i;
    arow[i] = q >> 3;
    akq[i] = q & 7;
    int r_loc = rt * 64 + arow[i];
    int tok = (r_loc < n_e) ? token_of[off_e + r_loc] : -1;
    aptr[i] = (tok >= 0) ? (x + (size_t)tok * HID + akq[i] * 4) : nullptr;
  }
  // B staging: cq = tid>>3 (col group of 4), kq = tid&7 (k group of 4)
  const int cq = tid >> 3, kq = tid & 7;
  const float* w1p = w1 + (size_t)e * HID * INTER + (size_t)(kq * 4) * INTER + col0 + cq * 4;
  const float* w3p = w3 + (size_t)e * HID * INTER + (size_t)(kq * 4) * INTER + col0 + cq * 4;

  const int lr = lane & 15, lg = lane >> 4;

  float4 av[2], b1v[4], b3v[4];
#define G1_LOAD(K0)                                                            \
  {                                                                            \
    _Pragma("unroll") for (int i = 0; i < 2; ++i) {                            \
      av[i] = make_float4(0.f, 0.f, 0.f, 0.f);                                 \
      if (aptr[i]) av[i] = *(const float4*)(aptr[i] + (K0));                   \
    }                                                                          \
    const float* p1 = w1p + (size_t)(K0)*INTER;                                \
    const float* p3 = w3p + (size_t)(K0)*INTER;                                \
    _Pragma("unroll") for (int r = 0; r < 4; ++r) {                            \
      b1v[r] = *(const float4*)(p1 + (size_t)r * INTER);                       \
      b3v[r] = *(const float4*)(p3 + (size_t)r * INTER);                       \
    }                                                                          \
  }

  G1_LOAD(0);
  for (int k0 = 0; k0 < HID; k0 += BK) {
    __syncthreads();
    // store staged regs -> LDS (fp32 -> bf16)
#pragma unroll
    for (int i = 0; i < 2; ++i) {
      float4 v = av[i];
      bf16x4 pv = {(__bf16)v.x, (__bf16)v.y, (__bf16)v.z, (__bf16)v.w};
      *(bf16x4*)&aL[arow[i]][akq[i] * 4] = pv;
    }
    TRANSPOSE_STORE(b1L, b1v[0], b1v[1], b1v[2], b1v[3], cq * 4, kq * 4);
    TRANSPOSE_STORE(b3L, b3v[0], b3v[1], b3v[2], b3v[3], cq * 4, kq * 4);
    __syncthreads();
    if (k0 + BK < HID) G1_LOAD(k0 + BK);  // prefetch next tile (overlaps MFMA below)
    // fragments + MFMA
    bf16x8 af[2], bf1[4], bf3[4];
#pragma unroll
    for (int m = 0; m < 2; ++m) af[m] = *(const bf16x8*)&aL[wr + m * 16 + lr][lg * 8];
#pragma unroll
    for (int n = 0; n < 4; ++n) {
      bf1[n] = *(const bf16x8*)&b1L[wc + n * 16 + lr][lg * 8];
      bf3[n] = *(const bf16x8*)&b3L[wc + n * 16 + lr][lg * 8];
    }
#pragma unroll
    for (int m = 0; m < 2; ++m)
#pragma unroll
      for (int n = 0; n < 4; ++n) {
        acc_h[m][n] = __builtin_amdgcn_mfma_f32_16x16x32_bf16(af[m], bf1[n], acc_h[m][n], 0, 0, 0);
        acc_u[m][n] = __builtin_amdgcn_mfma_f32_16x16x32_bf16(af[m], bf3[n], acc_u[m][n], 0, 0, 0);
      }
  }
#undef G1_LOAD

  // epilogue: a = silu(h) * u, store bf16
#pragma unroll
  for (int m = 0; m < 2; ++m)
#pragma unroll
    for (int n = 0; n < 4; ++n) {
      int col = col0 + wc + n * 16 + lr;
#pragma unroll
      for (int r = 0; r < 4; ++r) {
        int row_loc = rt * 64 + wr + m * 16 + lg * 4 + r;
        if (row_loc < n_e) {
          float h = acc_h[m][n][r];
          float u = acc_u[m][n][r];
          float a = h / (1.f + __expf(-h)) * u;
          abuf[(size_t)(off_e + row_loc) * INTER + col] = (__bf16)a;
        }
      }
    }
}

// ---------------- GEMM2: yp[sk] += gate * (a @ w2[kchunk]) ----------------
// BM=128, BN=128, split-K=4, 4 waves (2x2), wave tile 64x64
__global__ __launch_bounds__(256, 3) void moe_gemm2(
    const __bf16* __restrict__ abuf, const float* __restrict__ w2,
    const int* __restrict__ offsets, const int* __restrict__ counts,
    const int* __restrict__ token_of, const float* __restrict__ gate_of,
    float* __restrict__ yp) {
  const int e = blockIdx.z >> 2;
  const int sk = blockIdx.z & 3;
  const int n_e = counts[e];
  const int rt = blockIdx.y;
  if (rt * 128 >= n_e) return;
  const int off_e = offsets[e];
  const int col0 = blockIdx.x * 128;
  const int kbase = sk * KCHUNK;
  const int tid = threadIdx.x;
  const int lane = tid & 63;
  const int wid = tid >> 6;
  const int wr = (wid >> 1) * 64;
  const int wc = (wid & 1) * 64;

  __shared__ __bf16 aL[128][LDK];
  __shared__ __bf16 bL[128][LDK];

  f32x4 acc[4][4];
#pragma unroll
  for (int m = 0; m < 4; ++m)
#pragma unroll
    for (int n = 0; n < 4; ++n) acc[m][n] = (f32x4){0.f, 0.f, 0.f, 0.f};

  const __bf16* ap = abuf + (size_t)(off_e + rt * 128) * INTER + kbase;
  const int cq = tid >> 3, kq = tid & 7;
  const float* w2p =
      w2 + (size_t)e * INTER * HID + (size_t)(kbase + kq * 4) * HID + col0 + cq * 4;

  const int lr = lane & 15, lg = lane >> 4;

  bf16x8 av[2];
  float4 bv[4];
#define G2_LOAD(K0)                                                            \
  {                                                                            \
    _Pragma("unroll") for (int i = 0; i < 2; ++i) {                            \
      int q = tid + 256 * i;                                                   \
      av[i] = *(const bf16x8*)(ap + (size_t)(q >> 2) * INTER + (K0) + (q & 3) * 8); \
    }                                                                          \
    const float* p = w2p + (size_t)(K0)*HID;                                   \
    _Pragma("unroll") for (int r = 0; r < 4; ++r) {                            \
      bv[r] = *(const float4*)(p + (size_t)r * HID);                           \
    }                                                                          \
  }

  G2_LOAD(0);
  for (int k0 = 0; k0 < KCHUNK; k0 += BK) {
    __syncthreads();
#pragma unroll
    for (int i = 0; i < 2; ++i) {
      int q = tid + 256 * i;
      *(bf16x8*)&aL[q >> 2][(q & 3) * 8] = av[i];
    }
    TRANSPOSE_STORE(bL, bv[0], bv[1], bv[2], bv[3], cq * 4, kq * 4);
    __syncthreads();
    if (k0 + BK < KCHUNK) G2_LOAD(k0 + BK);  // prefetch next tile
    bf16x8 af[4], bf[4];
#pragma unroll
    for (int m = 0; m < 4; ++m) af[m] = *(const bf16x8*)&aL[wr + m * 16 + lr][lg * 8];
#pragma unroll
    for (int n = 0; n < 4; ++n) bf[n] = *(const bf16x8*)&bL[wc + n * 16 + lr][lg * 8];
#pragma unroll
    for (int m = 0; m < 4; ++m)
#pragma unroll
      for (int n = 0; n < 4; ++n)
        acc[m][n] = __builtin_amdgcn_mfma_f32_16x16x32_bf16(af[m], bf[n], acc[m][n], 0, 0, 0);
  }
#undef G2_LOAD

  // epilogue: yp[sk][token] += gate * y  (2 commutative adds per element -> deterministic)
  float* ypk = yp + (size_t)sk * T_TOK * HID;
#pragma unroll
  for (int m = 0; m < 4; ++m)
#pragma unroll
    for (int n = 0; n < 4; ++n) {
      int col = col0 + wc + n * 16 + lr;
#pragma unroll
      for (int r = 0; r < 4; ++r) {
        int row_loc = rt * 128 + wr + m * 16 + lg * 4 + r;
        if (row_loc < n_e) {
          int slot = off_e + row_loc;
          atomicAdd(&ypk[(size_t)token_of[slot] * HID + col], gate_of[slot] * acc[m][n][r]);
        }
      }
    }
}

// ---------------- combine: out = sum_sk yp[sk] (fixed order, deterministic) ----------------
__global__ void moe_combine(const float* __restrict__ yp, float* __restrict__ out) {
  int i = blockIdx.x * blockDim.x + threadIdx.x;  // float4 index
  const int N4 = T_TOK * HID / 4;
  if (i >= N4) return;
  const float4* p = (const float4*)yp;
  float4 a = p[i];
  float4 b = p[i + N4];
  float4 c = p[i + 2 * N4];
  float4 d = p[i + 3 * N4];
  float4 s;
  s.x = ((a.x + b.x) + c.x) + d.x;
  s.y = ((a.y + b.y) + c.y) + d.y;
  s.z = ((a.z + b.z) + c.z) + d.z;
  s.w = ((a.w + b.w) + c.w) + d.w;
  ((float4*)out)[i] = s;
}

// ---------------- launch ----------------
extern "C" void kernel_launch(void* const* d_in, const int* in_sizes, int n_in,
                              void* d_out, int out_size, void* d_ws, size_t ws_size,
                              hipStream_t stream) {
  const float* x = (const float*)d_in[0];
  const float* logits = (const float*)d_in[1];
  const float* w1 = (const float*)d_in[2];
  const float* w3 = (const float*)d_in[3];
  const float* w2 = (const float*)d_in[4];
  float* out = (float*)d_out;
  char* ws = (char*)d_ws;

  int* counts = (int*)(ws + WS_COUNTS);
  int* offsets = (int*)(ws + WS_OFFSETS);
  int* t_expert = (int*)(ws + WS_TEXPERT);
  float* t_gate = (float*)(ws + WS_TGATE);
  int* t_rank = (int*)(ws + WS_TRANK);
  int* token_of = (int*)(ws + WS_TOKEN_OF);
  float* gate_of = (float*)(ws + WS_GATE_OF);
  __bf16* abuf = (__bf16*)(ws + WS_ABUF);
  float* yp = (float*)(ws + WS_YP);

  hipMemsetAsync(counts, 0, 64, stream);
  hipMemsetAsync(yp, 0, (size_t)SPLITK * T_TOK * HID * 4, stream);
  moe_router<<<dim3(4), dim3(256), 0, stream>>>(logits, counts, t_expert, t_gate, t_rank);
  moe_assign<<<dim3(1), dim3(256), 0, stream>>>(counts, offsets, t_expert, t_gate, t_rank,
                                                token_of, gate_of);
  // gemm1: BM=64 -> y = ceil(1024/64) = 16 (worst-case expert size), early-exit otherwise
  moe_gemm1<<<dim3(INTER / 128, 16, NEXP), dim3(256), 0, stream>>>(x, w1, w3, offsets, counts,
                                                                   token_of, abuf);
  // gemm2: BM=128 -> y = 8 worst case; z = expert*4 + splitk
  moe_gemm2<<<dim3(HID / 128, 8, NEXP * SPLITK), dim3(256), 0, stream>>>(
      abuf, w2, offsets, counts, token_of, gate_of, yp);
  moe_combine<<<dim3((T_TOK * HID / 4 + 255) / 256), dim3(256), 0, stream>>>(yp, out);
}

// Round 4
// 169.289 us; speedup vs baseline: 1.2656x; 1.1988x over previous
//
#include <hip/hip_runtime.h>

#define T_TOK 1024
#define NEXP 8
#define HID 1024
#define INTER 2048
#define SLOT_CAP 2176  // abuf row allocation (with overrun slack)
#define NSLOT 2048     // exact slot count = T_TOK * 2
#define MAXTILES 40    // sum ceil(n_e/64) <= 2048/64 + 7 = 39

#define BK 32
#define LDK 40  // padded K stride in LDS (bf16 elems): 80B rows
#define SPLITK 2
#define KCHUNK (INTER / SPLITK)  // 1024

typedef __bf16 bf16x8 __attribute__((ext_vector_type(8)));
typedef __bf16 bf16x4 __attribute__((ext_vector_type(4)));
typedef float f32x4 __attribute__((ext_vector_type(4)));

// ---- workspace layout (bytes) ----
#define WS_COUNTS 0
#define WS_OFFSETS 64
#define WS_TEXPERT 128
#define WS_TGATE (WS_TEXPERT + T_TOK * 2 * 4)
#define WS_TRANK (WS_TGATE + T_TOK * 2 * 4)
#define WS_TOKEN_OF (WS_TRANK + T_TOK * 2 * 4)
#define WS_GATE_OF (WS_TOKEN_OF + SLOT_CAP * 4)
#define WS_SLOT_OF (WS_GATE_OF + SLOT_CAP * 4)
#define WS_TILE_E (WS_SLOT_OF + T_TOK * 2 * 4)
#define WS_TILE_R (WS_TILE_E + 256)
#define WS_NTILES (WS_TILE_R + 256)
#define WS_ABUF 65536                           // bf16 a[SLOT_CAP][INTER] = 8,912,896 B
#define WS_YS (WS_ABUF + SLOT_CAP * INTER * 2)  // fp32 ys[SPLITK][NSLOT][HID] = 16,777,216 B

// ---------------- router: softmax + top-2 ----------------
__global__ void moe_router(const float* __restrict__ logits, int* __restrict__ counts,
                           int* __restrict__ t_expert, float* __restrict__ t_gate,
                           int* __restrict__ t_rank) {
  int t = blockIdx.x * blockDim.x + threadIdx.x;
  if (t >= T_TOK) return;
  float l[NEXP];
  float mx = -1e30f;
#pragma unroll
  for (int e = 0; e < NEXP; ++e) {
    l[e] = logits[t * NEXP + e];
    mx = fmaxf(mx, l[e]);
  }
  float s = 0.f;
#pragma unroll
  for (int e = 0; e < NEXP; ++e) {
    l[e] = __expf(l[e] - mx);
    s += l[e];
  }
  float inv = 1.f / s;
  int i0 = 0;
#pragma unroll
  for (int e = 1; e < NEXP; ++e)
    if (l[e] > l[i0]) i0 = e;
  int i1 = (i0 == 0) ? 1 : 0;
#pragma unroll
  for (int e = 0; e < NEXP; ++e)
    if (e != i0 && e != i1 && l[e] > l[i1]) i1 = e;
  int es[2] = {i0, i1};
#pragma unroll
  for (int k = 0; k < 2; ++k) {
    int e = es[k];
    int r = atomicAdd(&counts[e], 1);
    int p = t * 2 + k;
    t_expert[p] = e;
    t_gate[p] = l[e] * inv;
    t_rank[p] = r;
  }
}

// ---------------- assign: prefix + slot maps + compact tile schedule ----------------
__global__ void moe_assign(const int* __restrict__ counts, int* __restrict__ offsets,
                           const int* __restrict__ t_expert, const float* __restrict__ t_gate,
                           const int* __restrict__ t_rank, int* __restrict__ token_of,
                           float* __restrict__ gate_of, int* __restrict__ slot_of,
                           int* __restrict__ tile_e, int* __restrict__ tile_r,
                           int* __restrict__ n_tiles) {
  __shared__ int off_s[NEXP];
  if (threadIdx.x == 0) {
    int s = 0, nt = 0;
    for (int e = 0; e < NEXP; ++e) {
      off_s[e] = s;
      offsets[e] = s;
      int ntile = (counts[e] + 63) >> 6;
      for (int r = 0; r < ntile; ++r) {
        tile_e[nt] = e;
        tile_r[nt] = r;
        ++nt;
      }
      s += counts[e];
    }
    *n_tiles = nt;
  }
  __syncthreads();
  for (int p = threadIdx.x; p < T_TOK * 2; p += blockDim.x) {
    int e = t_expert[p];
    int slot = off_s[e] + t_rank[p];
    token_of[slot] = p >> 1;
    gate_of[slot] = t_gate[p];
    slot_of[p] = slot;
  }
}

// transpose-convert a float4 row quad into 4 bf16 column chunks
#define TRANSPOSE_STORE(dst, r0, r1, r2, r3, cbase, kbase4)                    \
  {                                                                            \
    bf16x4 c0 = {(__bf16)r0.x, (__bf16)r1.x, (__bf16)r2.x, (__bf16)r3.x};      \
    bf16x4 c1 = {(__bf16)r0.y, (__bf16)r1.y, (__bf16)r2.y, (__bf16)r3.y};      \
    bf16x4 c2 = {(__bf16)r0.z, (__bf16)r1.z, (__bf16)r2.z, (__bf16)r3.z};      \
    bf16x4 c3 = {(__bf16)r0.w, (__bf16)r1.w, (__bf16)r2.w, (__bf16)r3.w};      \
    *(bf16x4*)&dst[(cbase) + 0][kbase4] = c0;                                  \
    *(bf16x4*)&dst[(cbase) + 1][kbase4] = c1;                                  \
    *(bf16x4*)&dst[(cbase) + 2][kbase4] = c2;                                  \
    *(bf16x4*)&dst[(cbase) + 3][kbase4] = c3;                                  \
  }

// ---------------- GEMM1: h,u = Xg @ {w1,w3}; a = silu(h)*u ----------------
// BM=64, BN=64, 4 waves (2x2), wave tile 32x32; compact tile grid
__global__ __launch_bounds__(256, 2) void moe_gemm1(
    const float* __restrict__ x, const float* __restrict__ w1, const float* __restrict__ w3,
    const int* __restrict__ offsets, const int* __restrict__ counts,
    const int* __restrict__ token_of, const int* __restrict__ tile_e,
    const int* __restrict__ tile_r, const int* __restrict__ n_tiles,
    __bf16* __restrict__ abuf) {
  if ((int)blockIdx.y >= *n_tiles) return;
  const int e = tile_e[blockIdx.y];
  const int rt = tile_r[blockIdx.y];
  const int n_e = counts[e];
  const int off_e = offsets[e];
  const int col0 = blockIdx.x * 64;
  const int tid = threadIdx.x;
  const int lane = tid & 63;
  const int wid = tid >> 6;
  const int wr = (wid >> 1) * 32;
  const int wc = (wid & 1) * 32;

  __shared__ __bf16 aL[64][LDK];
  __shared__ __bf16 b1L[64][LDK];
  __shared__ __bf16 b3L[64][LDK];

  f32x4 acc_h[2][2], acc_u[2][2];
#pragma unroll
  for (int m = 0; m < 2; ++m)
#pragma unroll
    for (int n = 0; n < 2; ++n) {
      acc_h[m][n] = (f32x4){0.f, 0.f, 0.f, 0.f};
      acc_u[m][n] = (f32x4){0.f, 0.f, 0.f, 0.f};
    }

  // A staging: 64 rows x 8 float4-chunks = 512; thread does 2
  const float* aptr[2];
  int arow[2], akq[2];
#pragma unroll
  for (int i = 0; i < 2; ++i) {
    int q = tid + 256 * i;
    arow[i] = q >> 3;
    akq[i] = q & 7;
    int r_loc = rt * 64 + arow[i];
    int tok = (r_loc < n_e) ? token_of[off_e + r_loc] : -1;
    aptr[i] = (tok >= 0) ? (x + (size_t)tok * HID + akq[i] * 4) : nullptr;
  }
  // B staging: half the block does w1, half w3; 32k x 64col fp32 each
  const int bsel = tid >> 7;  // 0: w1, 1: w3
  const int sub = tid & 127;
  const int bcq = sub >> 3;  // 0..15 col group
  const int bkq = sub & 7;   // 0..7  k group (rows bkq*4..+3)
  const float* wp = (bsel ? w3 : w1) + (size_t)e * HID * INTER +
                    (size_t)(bkq * 4) * INTER + col0 + bcq * 4;
  __bf16(*bdst)[LDK] = bsel ? b3L : b1L;

  const int lr = lane & 15, lg = lane >> 4;

  float4 av[2], bv[4];
#define G1_LOAD(K0)                                                            \
  {                                                                            \
    _Pragma("unroll") for (int i = 0; i < 2; ++i) {                            \
      av[i] = make_float4(0.f, 0.f, 0.f, 0.f);                                 \
      if (aptr[i]) av[i] = *(const float4*)(aptr[i] + (K0));                   \
    }                                                                          \
    const float* p = wp + (size_t)(K0)*INTER;                                  \
    _Pragma("unroll") for (int r = 0; r < 4; ++r) {                            \
      bv[r] = *(const float4*)(p + (size_t)r * INTER);                         \
    }                                                                          \
  }

  G1_LOAD(0);
  for (int k0 = 0; k0 < HID; k0 += BK) {
    __syncthreads();
#pragma unroll
    for (int i = 0; i < 2; ++i) {
      float4 v = av[i];
      bf16x4 pv = {(__bf16)v.x, (__bf16)v.y, (__bf16)v.z, (__bf16)v.w};
      *(bf16x4*)&aL[arow[i]][akq[i] * 4] = pv;
    }
    TRANSPOSE_STORE(bdst, bv[0], bv[1], bv[2], bv[3], bcq * 4, bkq * 4);
    __syncthreads();
    if (k0 + BK < HID) G1_LOAD(k0 + BK);  // prefetch next tile
    bf16x8 af[2], bf1[2], bf3[2];
#pragma unroll
    for (int m = 0; m < 2; ++m) af[m] = *(const bf16x8*)&aL[wr + m * 16 + lr][lg * 8];
#pragma unroll
    for (int n = 0; n < 2; ++n) {
      bf1[n] = *(const bf16x8*)&b1L[wc + n * 16 + lr][lg * 8];
      bf3[n] = *(const bf16x8*)&b3L[wc + n * 16 + lr][lg * 8];
    }
#pragma unroll
    for (int m = 0; m < 2; ++m)
#pragma unroll
      for (int n = 0; n < 2; ++n) {
        acc_h[m][n] = __builtin_amdgcn_mfma_f32_16x16x32_bf16(af[m], bf1[n], acc_h[m][n], 0, 0, 0);
        acc_u[m][n] = __builtin_amdgcn_mfma_f32_16x16x32_bf16(af[m], bf3[n], acc_u[m][n], 0, 0, 0);
      }
  }
#undef G1_LOAD

  // epilogue: a = silu(h) * u, store bf16
#pragma unroll
  for (int m = 0; m < 2; ++m)
#pragma unroll
    for (int n = 0; n < 2; ++n) {
      int col = col0 + wc + n * 16 + lr;
#pragma unroll
      for (int r = 0; r < 4; ++r) {
        int row_loc = rt * 64 + wr + m * 16 + lg * 4 + r;
        if (row_loc < n_e) {
          float h = acc_h[m][n][r];
          float u = acc_u[m][n][r];
          float a = h / (1.f + __expf(-h)) * u;
          abuf[(size_t)(off_e + row_loc) * INTER + col] = (__bf16)a;
        }
      }
    }
}

// ---------------- GEMM2: ys[sk][slot] = gate * (a @ w2[kchunk]) ----------------
// BM=64, BN=64, split-K=2, 4 waves (2x2), wave tile 32x32; compact tile grid
__global__ __launch_bounds__(256, 2) void moe_gemm2(
    const __bf16* __restrict__ abuf, const float* __restrict__ w2,
    const int* __restrict__ offsets, const int* __restrict__ counts,
    const float* __restrict__ gate_of, const int* __restrict__ tile_e,
    const int* __restrict__ tile_r, const int* __restrict__ n_tiles,
    float* __restrict__ yslot) {
  if ((int)blockIdx.y >= *n_tiles) return;
  const int e = tile_e[blockIdx.y];
  const int rt = tile_r[blockIdx.y];
  const int sk = blockIdx.z;
  const int n_e = counts[e];
  const int off_e = offsets[e];
  const int col0 = blockIdx.x * 64;
  const int kbase = sk * KCHUNK;
  const int tid = threadIdx.x;
  const int lane = tid & 63;
  const int wid = tid >> 6;
  const int wr = (wid >> 1) * 32;
  const int wc = (wid & 1) * 32;

  __shared__ __bf16 aL[64][LDK];
  __shared__ __bf16 bL[64][LDK];

  f32x4 acc[2][2];
#pragma unroll
  for (int m = 0; m < 2; ++m)
#pragma unroll
    for (int n = 0; n < 2; ++n) acc[m][n] = (f32x4){0.f, 0.f, 0.f, 0.f};

  // A staging: 64 rows x 4 bf16x8-chunks = 256; thread does 1
  const int arow = tid >> 2, akc = tid & 3;
  const __bf16* ap =
      abuf + (size_t)(off_e + rt * 64) * INTER + kbase + (size_t)arow * INTER + akc * 8;
  // B staging: threads 0..127; 32k x 64col fp32
  const int bcq = (tid & 127) >> 3, bkq = tid & 7;
  const float* w2p = w2 + (size_t)e * INTER * HID + (size_t)(kbase + bkq * 4) * HID +
                     col0 + bcq * 4;

  const int lr = lane & 15, lg = lane >> 4;

  bf16x8 av;
  float4 bv[4];
#define G2_LOAD(K0)                                                            \
  {                                                                            \
    av = *(const bf16x8*)(ap + (K0));                                         \
    if (tid < 128) {                                                           \
      const float* p = w2p + (size_t)(K0)*HID;                                 \
      _Pragma("unroll") for (int r = 0; r < 4; ++r) {                          \
        bv[r] = *(const float4*)(p + (size_t)r * HID);                         \
      }                                                                        \
    }                                                                          \
  }

  G2_LOAD(0);
  for (int k0 = 0; k0 < KCHUNK; k0 += BK) {
    __syncthreads();
    *(bf16x8*)&aL[arow][akc * 8] = av;
    if (tid < 128) TRANSPOSE_STORE(bL, bv[0], bv[1], bv[2], bv[3], bcq * 4, bkq * 4);
    __syncthreads();
    if (k0 + BK < KCHUNK) G2_LOAD(k0 + BK);  // prefetch next tile
    bf16x8 af[2], bf[2];
#pragma unroll
    for (int m = 0; m < 2; ++m) af[m] = *(const bf16x8*)&aL[wr + m * 16 + lr][lg * 8];
#pragma unroll
    for (int n = 0; n < 2; ++n) bf[n] = *(const bf16x8*)&bL[wc + n * 16 + lr][lg * 8];
#pragma unroll
    for (int m = 0; m < 2; ++m)
#pragma unroll
      for (int n = 0; n < 2; ++n)
        acc[m][n] = __builtin_amdgcn_mfma_f32_16x16x32_bf16(af[m], bf[n], acc[m][n], 0, 0, 0);
  }
#undef G2_LOAD

  // epilogue: plain stores, each (sk,slot,col) written exactly once
  float* ysk = yslot + (size_t)sk * NSLOT * HID;
#pragma unroll
  for (int m = 0; m < 2; ++m)
#pragma unroll
    for (int n = 0; n < 2; ++n) {
      int col = col0 + wc + n * 16 + lr;
#pragma unroll
      for (int r = 0; r < 4; ++r) {
        int row_loc = rt * 64 + wr + m * 16 + lg * 4 + r;
        if (row_loc < n_e) {
          int slot = off_e + row_loc;
          ysk[(size_t)slot * HID + col] = gate_of[slot] * acc[m][n][r];
        }
      }
    }
}

// ---------------- combine: out[t] = sum over (k, sk) of ys, fixed order ----------------
__global__ void moe_combine(const float* __restrict__ yslot, const int* __restrict__ slot_of,
                            float* __restrict__ out) {
  int i = blockIdx.x * blockDim.x + threadIdx.x;  // float4 index over [T][H]
  const int N4 = T_TOK * HID / 4;
  if (i >= N4) return;
  int t = i >> 8;        // HID/4 = 256 float4 per row
  int c4 = i & 255;
  int sA = slot_of[2 * t];
  int sB = slot_of[2 * t + 1];
  const float4* ys0 = (const float4*)yslot;
  const float4* ys1 = (const float4*)(yslot + (size_t)NSLOT * HID);
  float4 a = ys0[(size_t)sA * 256 + c4];
  float4 b = ys0[(size_t)sB * 256 + c4];
  float4 c = ys1[(size_t)sA * 256 + c4];
  float4 d = ys1[(size_t)sB * 256 + c4];
  float4 s;
  s.x = ((a.x + b.x) + c.x) + d.x;
  s.y = ((a.y + b.y) + c.y) + d.y;
  s.z = ((a.z + b.z) + c.z) + d.z;
  s.w = ((a.w + b.w) + c.w) + d.w;
  ((float4*)out)[i] = s;
}

// ---------------- launch ----------------
extern "C" void kernel_launch(void* const* d_in, const int* in_sizes, int n_in,
                              void* d_out, int out_size, void* d_ws, size_t ws_size,
                              hipStream_t stream) {
  const float* x = (const float*)d_in[0];
  const float* logits = (const float*)d_in[1];
  const float* w1 = (const float*)d_in[2];
  const float* w3 = (const float*)d_in[3];
  const float* w2 = (const float*)d_in[4];
  float* out = (float*)d_out;
  char* ws = (char*)d_ws;

  int* counts = (int*)(ws + WS_COUNTS);
  int* offsets = (int*)(ws + WS_OFFSETS);
  int* t_expert = (int*)(ws + WS_TEXPERT);
  float* t_gate = (float*)(ws + WS_TGATE);
  int* t_rank = (int*)(ws + WS_TRANK);
  int* token_of = (int*)(ws + WS_TOKEN_OF);
  float* gate_of = (float*)(ws + WS_GATE_OF);
  int* slot_of = (int*)(ws + WS_SLOT_OF);
  int* tile_e = (int*)(ws + WS_TILE_E);
  int* tile_r = (int*)(ws + WS_TILE_R);
  int* n_tiles = (int*)(ws + WS_NTILES);
  __bf16* abuf = (__bf16*)(ws + WS_ABUF);
  float* yslot = (float*)(ws + WS_YS);

  hipMemsetAsync(counts, 0, 64, stream);
  moe_router<<<dim3(4), dim3(256), 0, stream>>>(logits, counts, t_expert, t_gate, t_rank);
  moe_assign<<<dim3(1), dim3(256), 0, stream>>>(counts, offsets, t_expert, t_gate, t_rank,
                                                token_of, gate_of, slot_of, tile_e, tile_r,
                                                n_tiles);
  moe_gemm1<<<dim3(INTER / 64, MAXTILES), dim3(256), 0, stream>>>(
      x, w1, w3, offsets, counts, token_of, tile_e, tile_r, n_tiles, abuf);
  moe_gemm2<<<dim3(HID / 64, MAXTILES, SPLITK), dim3(256), 0, stream>>>(
      abuf, w2, offsets, counts, gate_of, tile_e, tile_r, n_tiles, yslot);
  moe_combine<<<dim3((T_TOK * HID / 4 + 255) / 256), dim3(256), 0, stream>>>(yslot, slot_of,
                                                                             out);
}

// Round 5
// 139.849 us; speedup vs baseline: 1.5320x; 1.2105x over previous
//
#include <hip/hip_runtime.h>

#define T_TOK 1024
#define NEXP 8
#define HID 1024
#define INTER 2048
#define SLOT_CAP 2176  // row allocation slack for tail tiles
#define NSLOT 2048     // exact slot count = T_TOK * 2
#define MAXTILES 24    // sum ceil(n_e/128) <= 2048/128 + 8 = 24

#define BK 32
#define LDK 40  // padded K stride in LDS (bf16 elems): 80B rows
#define SPLITK 2
#define KCHUNK (INTER / SPLITK)  // 1024

typedef __bf16 bf16x8 __attribute__((ext_vector_type(8)));
typedef __bf16 bf16x4 __attribute__((ext_vector_type(4)));
typedef float f32x4 __attribute__((ext_vector_type(4)));

// ---- workspace layout (bytes) ----
#define WS_COUNTS 0
#define WS_OFFSETS 64
#define WS_TEXPERT 128
#define WS_TGATE (WS_TEXPERT + T_TOK * 2 * 4)
#define WS_TRANK (WS_TGATE + T_TOK * 2 * 4)
#define WS_TOKEN_OF (WS_TRANK + T_TOK * 2 * 4)
#define WS_GATE_OF (WS_TOKEN_OF + SLOT_CAP * 4)
#define WS_SLOT_OF (WS_GATE_OF + SLOT_CAP * 4)
#define WS_TILE_E (WS_SLOT_OF + T_TOK * 2 * 4)
#define WS_TILE_R (WS_TILE_E + 256)
#define WS_NTILES (WS_TILE_R + 256)
#define WS_ABUF 65536                           // bf16 a[SLOT_CAP][INTER] = 8,912,896 B
#define WS_YS (WS_ABUF + SLOT_CAP * INTER * 2)  // fp32 ys[SPLITK][NSLOT][HID] = 16,777,216 B
// xg (bf16 [SLOT_CAP][HID] = 4.46 MB) aliases the YS region: xg is consumed by gemm1
// before gemm2 writes ys, so the alias is safe and saves workspace.

// ---------------- router: softmax + top-2 ----------------
__global__ void moe_router(const float* __restrict__ logits, int* __restrict__ counts,
                           int* __restrict__ t_expert, float* __restrict__ t_gate,
                           int* __restrict__ t_rank) {
  int t = blockIdx.x * blockDim.x + threadIdx.x;
  if (t >= T_TOK) return;
  float l[NEXP];
  float mx = -1e30f;
#pragma unroll
  for (int e = 0; e < NEXP; ++e) {
    l[e] = logits[t * NEXP + e];
    mx = fmaxf(mx, l[e]);
  }
  float s = 0.f;
#pragma unroll
  for (int e = 0; e < NEXP; ++e) {
    l[e] = __expf(l[e] - mx);
    s += l[e];
  }
  float inv = 1.f / s;
  int i0 = 0;
#pragma unroll
  for (int e = 1; e < NEXP; ++e)
    if (l[e] > l[i0]) i0 = e;
  int i1 = (i0 == 0) ? 1 : 0;
#pragma unroll
  for (int e = 0; e < NEXP; ++e)
    if (e != i0 && e != i1 && l[e] > l[i1]) i1 = e;
  int es[2] = {i0, i1};
#pragma unroll
  for (int k = 0; k < 2; ++k) {
    int e = es[k];
    int r = atomicAdd(&counts[e], 1);
    int p = t * 2 + k;
    t_expert[p] = e;
    t_gate[p] = l[e] * inv;
    t_rank[p] = r;
  }
}

// ---------------- assign: prefix + slot maps + compact tile schedule ----------------
__global__ void moe_assign(const int* __restrict__ counts, int* __restrict__ offsets,
                           const int* __restrict__ t_expert, const float* __restrict__ t_gate,
                           const int* __restrict__ t_rank, int* __restrict__ token_of,
                           float* __restrict__ gate_of, int* __restrict__ slot_of,
                           int* __restrict__ tile_e, int* __restrict__ tile_r,
                           int* __restrict__ n_tiles) {
  __shared__ int off_s[NEXP];
  if (threadIdx.x == 0) {
    int s = 0, nt = 0;
    for (int e = 0; e < NEXP; ++e) {
      off_s[e] = s;
      offsets[e] = s;
      int ntile = (counts[e] + 127) >> 7;  // BM=128 tiles
      for (int r = 0; r < ntile; ++r) {
        tile_e[nt] = e;
        tile_r[nt] = r;
        ++nt;
      }
      s += counts[e];
    }
    *n_tiles = nt;
  }
  __syncthreads();
  for (int p = threadIdx.x; p < T_TOK * 2; p += blockDim.x) {
    int e = t_expert[p];
    int slot = off_s[e] + t_rank[p];
    token_of[slot] = p >> 1;
    gate_of[slot] = t_gate[p];
    slot_of[p] = slot;
  }
}

// ---------------- xgather: xg[slot] = bf16(x[token_of[slot]]) ----------------
__global__ void moe_xgather(const float* __restrict__ x, const int* __restrict__ token_of,
                            __bf16* __restrict__ xg) {
  int idx = blockIdx.x * blockDim.x + threadIdx.x;  // 0 .. 2048*128-1
  int slot = idx >> 7;
  int c = (idx & 127) * 8;
  const float* src = x + (size_t)token_of[slot] * HID + c;
  float4 v0 = *(const float4*)src;
  float4 v1 = *(const float4*)(src + 4);
  bf16x8 o = {(__bf16)v0.x, (__bf16)v0.y, (__bf16)v0.z, (__bf16)v0.w,
              (__bf16)v1.x, (__bf16)v1.y, (__bf16)v1.z, (__bf16)v1.w};
  *(bf16x8*)&xg[(size_t)slot * HID + c] = o;
}

// transpose-convert a float4 row quad into 4 bf16 column chunks
#define TRANSPOSE_STORE(dst, r0, r1, r2, r3, cbase, kbase4)                    \
  {                                                                            \
    bf16x4 c0 = {(__bf16)r0.x, (__bf16)r1.x, (__bf16)r2.x, (__bf16)r3.x};      \
    bf16x4 c1 = {(__bf16)r0.y, (__bf16)r1.y, (__bf16)r2.y, (__bf16)r3.y};      \
    bf16x4 c2 = {(__bf16)r0.z, (__bf16)r1.z, (__bf16)r2.z, (__bf16)r3.z};      \
    bf16x4 c3 = {(__bf16)r0.w, (__bf16)r1.w, (__bf16)r2.w, (__bf16)r3.w};      \
    *(bf16x4*)&dst[(cbase) + 0][kbase4] = c0;                                  \
    *(bf16x4*)&dst[(cbase) + 1][kbase4] = c1;                                  \
    *(bf16x4*)&dst[(cbase) + 2][kbase4] = c2;                                  \
    *(bf16x4*)&dst[(cbase) + 3][kbase4] = c3;                                  \
  }

// ---------------- GEMM1: h,u = Xg @ {w1,w3}; a = silu(h)*u ----------------
// BM=128, BN=64, 4 waves (2 row x 2 col), wave tile 64x32
__global__ __launch_bounds__(256, 3) void moe_gemm1(
    const __bf16* __restrict__ xg, const float* __restrict__ w1, const float* __restrict__ w3,
    const int* __restrict__ offsets, const int* __restrict__ counts,
    const int* __restrict__ tile_e, const int* __restrict__ tile_r,
    const int* __restrict__ n_tiles, __bf16* __restrict__ abuf) {
  if ((int)blockIdx.y >= *n_tiles) return;
  const int e = tile_e[blockIdx.y];
  const int rt = tile_r[blockIdx.y];
  const int n_e = counts[e];
  const int off_e = offsets[e];
  const int col0 = blockIdx.x * 64;
  const int tid = threadIdx.x;
  const int lane = tid & 63;
  const int wid = tid >> 6;
  const int wr = (wid >> 1) * 64;
  const int wc = (wid & 1) * 32;

  __shared__ __bf16 aL[128][LDK];
  __shared__ __bf16 b1L[64][LDK];
  __shared__ __bf16 b3L[64][LDK];

  f32x4 acc_h[4][2], acc_u[4][2];
#pragma unroll
  for (int m = 0; m < 4; ++m)
#pragma unroll
    for (int n = 0; n < 2; ++n) {
      acc_h[m][n] = (f32x4){0.f, 0.f, 0.f, 0.f};
      acc_u[m][n] = (f32x4){0.f, 0.f, 0.f, 0.f};
    }

  // A staging: row = tid>>1 (0..127), 16-elem chunk = tid&1; contiguous bf16 from xg
  const int arow = tid >> 1, achk = (tid & 1) * 16;
  const __bf16* ap = xg + (size_t)(off_e + rt * 128 + arow) * HID + achk;
  // B staging: half block w1, half w3; per thread one (4col x 4k) cell
  const int bsel = tid >> 7;  // 0: w1, 1: w3
  const int sub = tid & 127;
  const int bcq = sub >> 3;  // 0..15 col group
  const int bkq = sub & 7;   // 0..7  k group
  const float* wp = (bsel ? w3 : w1) + (size_t)e * HID * INTER +
                    (size_t)(bkq * 4) * INTER + col0 + bcq * 4;
  __bf16(*bdst)[LDK] = bsel ? b3L : b1L;

  const int lr = lane & 15, lg = lane >> 4;

  bf16x8 av[2];
  float4 bv[4];
#define G1_LOAD(K0)                                                            \
  {                                                                            \
    av[0] = *(const bf16x8*)(ap + (K0));                                       \
    av[1] = *(const bf16x8*)(ap + (K0) + 8);                                   \
    const float* p = wp + (size_t)(K0)*INTER;                                  \
    _Pragma("unroll") for (int r = 0; r < 4; ++r) {                            \
      bv[r] = *(const float4*)(p + (size_t)r * INTER);                         \
    }                                                                          \
  }

  G1_LOAD(0);
  for (int k0 = 0; k0 < HID; k0 += BK) {
    __syncthreads();
    *(bf16x8*)&aL[arow][achk] = av[0];
    *(bf16x8*)&aL[arow][achk + 8] = av[1];
    TRANSPOSE_STORE(bdst, bv[0], bv[1], bv[2], bv[3], bcq * 4, bkq * 4);
    __syncthreads();
    if (k0 + BK < HID) G1_LOAD(k0 + BK);  // prefetch next tile
    bf16x8 af[4], bf1[2], bf3[2];
#pragma unroll
    for (int m = 0; m < 4; ++m) af[m] = *(const bf16x8*)&aL[wr + m * 16 + lr][lg * 8];
#pragma unroll
    for (int n = 0; n < 2; ++n) {
      bf1[n] = *(const bf16x8*)&b1L[wc + n * 16 + lr][lg * 8];
      bf3[n] = *(const bf16x8*)&b3L[wc + n * 16 + lr][lg * 8];
    }
#pragma unroll
    for (int m = 0; m < 4; ++m)
#pragma unroll
      for (int n = 0; n < 2; ++n) {
        acc_h[m][n] = __builtin_amdgcn_mfma_f32_16x16x32_bf16(af[m], bf1[n], acc_h[m][n], 0, 0, 0);
        acc_u[m][n] = __builtin_amdgcn_mfma_f32_16x16x32_bf16(af[m], bf3[n], acc_u[m][n], 0, 0, 0);
      }
  }
#undef G1_LOAD

  // epilogue: a = silu(h) * u, store bf16
#pragma unroll
  for (int m = 0; m < 4; ++m)
#pragma unroll
    for (int n = 0; n < 2; ++n) {
      int col = col0 + wc + n * 16 + lr;
#pragma unroll
      for (int r = 0; r < 4; ++r) {
        int row_loc = rt * 128 + wr + m * 16 + lg * 4 + r;
        if (row_loc < n_e) {
          float h = acc_h[m][n][r];
          float u = acc_u[m][n][r];
          float a = h / (1.f + __expf(-h)) * u;
          abuf[(size_t)(off_e + row_loc) * INTER + col] = (__bf16)a;
        }
      }
    }
}

// ---------------- GEMM2: ys[sk][slot] = gate * (a @ w2[kchunk]) ----------------
// BM=128, BN=64, split-K=2, 4 waves (2x2), wave tile 64x32
__global__ __launch_bounds__(256, 4) void moe_gemm2(
    const __bf16* __restrict__ abuf, const float* __restrict__ w2,
    const int* __restrict__ offsets, const int* __restrict__ counts,
    const float* __restrict__ gate_of, const int* __restrict__ tile_e,
    const int* __restrict__ tile_r, const int* __restrict__ n_tiles,
    float* __restrict__ yslot) {
  if ((int)blockIdx.y >= *n_tiles) return;
  const int e = tile_e[blockIdx.y];
  const int rt = tile_r[blockIdx.y];
  const int sk = blockIdx.z;
  const int n_e = counts[e];
  const int off_e = offsets[e];
  const int col0 = blockIdx.x * 64;
  const int kbase = sk * KCHUNK;
  const int tid = threadIdx.x;
  const int lane = tid & 63;
  const int wid = tid >> 6;
  const int wr = (wid >> 1) * 64;
  const int wc = (wid & 1) * 32;

  __shared__ __bf16 aL[128][LDK];
  __shared__ __bf16 bL[64][LDK];

  f32x4 acc[4][2];
#pragma unroll
  for (int m = 0; m < 4; ++m)
#pragma unroll
    for (int n = 0; n < 2; ++n) acc[m][n] = (f32x4){0.f, 0.f, 0.f, 0.f};

  // A staging: row = tid>>1, 16-elem chunk = tid&1 (bf16 contiguous)
  const int arow = tid >> 1, achk = (tid & 1) * 16;
  const __bf16* ap = abuf + (size_t)(off_e + rt * 128 + arow) * INTER + kbase + achk;
  // B staging: threads 0..127, one (4col x 4k) cell each
  const int bcq = (tid & 127) >> 3, bkq = tid & 7;
  const float* w2p =
      w2 + (size_t)e * INTER * HID + (size_t)(kbase + bkq * 4) * HID + col0 + bcq * 4;

  const int lr = lane & 15, lg = lane >> 4;

  bf16x8 av[2];
  float4 bv[4];
#define G2_LOAD(K0)                                                            \
  {                                                                            \
    av[0] = *(const bf16x8*)(ap + (K0));                                       \
    av[1] = *(const bf16x8*)(ap + (K0) + 8);                                   \
    if (tid < 128) {                                                           \
      const float* p = w2p + (size_t)(K0)*HID;                                 \
      _Pragma("unroll") for (int r = 0; r < 4; ++r) {                          \
        bv[r] = *(const float4*)(p + (size_t)r * HID);                         \
      }                                                                        \
    }                                                                          \
  }

  G2_LOAD(0);
  for (int k0 = 0; k0 < KCHUNK; k0 += BK) {
    __syncthreads();
    *(bf16x8*)&aL[arow][achk] = av[0];
    *(bf16x8*)&aL[arow][achk + 8] = av[1];
    if (tid < 128) TRANSPOSE_STORE(bL, bv[0], bv[1], bv[2], bv[3], bcq * 4, bkq * 4);
    __syncthreads();
    if (k0 + BK < KCHUNK) G2_LOAD(k0 + BK);  // prefetch next tile
    bf16x8 af[4], bf[2];
#pragma unroll
    for (int m = 0; m < 4; ++m) af[m] = *(const bf16x8*)&aL[wr + m * 16 + lr][lg * 8];
#pragma unroll
    for (int n = 0; n < 2; ++n) bf[n] = *(const bf16x8*)&bL[wc + n * 16 + lr][lg * 8];
#pragma unroll
    for (int m = 0; m < 4; ++m)
#pragma unroll
      for (int n = 0; n < 2; ++n)
        acc[m][n] = __builtin_amdgcn_mfma_f32_16x16x32_bf16(af[m], bf[n], acc[m][n], 0, 0, 0);
  }
#undef G2_LOAD

  // epilogue: plain stores, each (sk,slot,col) written exactly once
  float* ysk = yslot + (size_t)sk * NSLOT * HID;
#pragma unroll
  for (int m = 0; m < 4; ++m)
#pragma unroll
    for (int n = 0; n < 2; ++n) {
      int col = col0 + wc + n * 16 + lr;
#pragma unroll
      for (int r = 0; r < 4; ++r) {
        int row_loc = rt * 128 + wr + m * 16 + lg * 4 + r;
        if (row_loc < n_e) {
          int slot = off_e + row_loc;
          ysk[(size_t)slot * HID + col] = gate_of[slot] * acc[m][n][r];
        }
      }
    }
}

// ---------------- combine: out[t] = sum over (k, sk) of ys, fixed order ----------------
__global__ void moe_combine(const float* __restrict__ yslot, const int* __restrict__ slot_of,
                            float* __restrict__ out) {
  int i = blockIdx.x * blockDim.x + threadIdx.x;  // float4 index over [T][H]
  const int N4 = T_TOK * HID / 4;
  if (i >= N4) return;
  int t = i >> 8;  // HID/4 = 256 float4 per row
  int c4 = i & 255;
  int sA = slot_of[2 * t];
  int sB = slot_of[2 * t + 1];
  const float4* ys0 = (const float4*)yslot;
  const float4* ys1 = (const float4*)(yslot + (size_t)NSLOT * HID);
  float4 a = ys0[(size_t)sA * 256 + c4];
  float4 b = ys0[(size_t)sB * 256 + c4];
  float4 c = ys1[(size_t)sA * 256 + c4];
  float4 d = ys1[(size_t)sB * 256 + c4];
  float4 s;
  s.x = ((a.x + b.x) + c.x) + d.x;
  s.y = ((a.y + b.y) + c.y) + d.y;
  s.z = ((a.z + b.z) + c.z) + d.z;
  s.w = ((a.w + b.w) + c.w) + d.w;
  ((float4*)out)[i] = s;
}

// ---------------- launch ----------------
extern "C" void kernel_launch(void* const* d_in, const int* in_sizes, int n_in,
                              void* d_out, int out_size, void* d_ws, size_t ws_size,
                              hipStream_t stream) {
  const float* x = (const float*)d_in[0];
  const float* logits = (const float*)d_in[1];
  const float* w1 = (const float*)d_in[2];
  const float* w3 = (const float*)d_in[3];
  const float* w2 = (const float*)d_in[4];
  float* out = (float*)d_out;
  char* ws = (char*)d_ws;

  int* counts = (int*)(ws + WS_COUNTS);
  int* offsets = (int*)(ws + WS_OFFSETS);
  int* t_expert = (int*)(ws + WS_TEXPERT);
  float* t_gate = (float*)(ws + WS_TGATE);
  int* t_rank = (int*)(ws + WS_TRANK);
  int* token_of = (int*)(ws + WS_TOKEN_OF);
  float* gate_of = (float*)(ws + WS_GATE_OF);
  int* slot_of = (int*)(ws + WS_SLOT_OF);
  int* tile_e = (int*)(ws + WS_TILE_E);
  int* tile_r = (int*)(ws + WS_TILE_R);
  int* n_tiles = (int*)(ws + WS_NTILES);
  __bf16* abuf = (__bf16*)(ws + WS_ABUF);
  float* yslot = (float*)(ws + WS_YS);
  __bf16* xg = (__bf16*)(ws + WS_YS);  // alias: xg dead before gemm2 writes ys

  hipMemsetAsync(counts, 0, 64, stream);
  moe_router<<<dim3(4), dim3(256), 0, stream>>>(logits, counts, t_expert, t_gate, t_rank);
  moe_assign<<<dim3(1), dim3(256), 0, stream>>>(counts, offsets, t_expert, t_gate, t_rank,
                                                token_of, gate_of, slot_of, tile_e, tile_r,
                                                n_tiles);
  moe_xgather<<<dim3(NSLOT * (HID / 8) / 256), dim3(256), 0, stream>>>(x, token_of, xg);
  moe_gemm1<<<dim3(INTER / 64, MAXTILES), dim3(256), 0, stream>>>(
      xg, w1, w3, offsets, counts, tile_e, tile_r, n_tiles, abuf);
  moe_gemm2<<<dim3(HID / 64, MAXTILES, SPLITK), dim3(256), 0, stream>>>(
      abuf, w2, offsets, counts, gate_of, tile_e, tile_r, n_tiles, yslot);
  moe_combine<<<dim3((T_TOK * HID / 4 + 255) / 256), dim3(256), 0, stream>>>(yslot, slot_of,
                                                                             out);
}